// Round 1
// baseline (6715.798 us; speedup 1.0000x reference)
//
#include <hip/hip_runtime.h>
#include <math.h>

#define T_    2048
#define H_    2048
#define NH_   16
#define NKV_  4
#define HD_   128
#define I_    1024
#define E_    16
#define QKVN  3072
#define EPS_  1e-5f

// ---------------- RMSNorm: one block per row ----------------
__global__ __launch_bounds__(256) void rmsnorm_k(const float* __restrict__ x,
                                                 const float* __restrict__ w,
                                                 float* __restrict__ out) {
  int t = blockIdx.x;
  const float* xr = x + (size_t)t * H_;
  float ss = 0.f;
  for (int c = threadIdx.x; c < H_; c += 256) { float v = xr[c]; ss += v * v; }
#pragma unroll
  for (int off = 32; off > 0; off >>= 1) ss += __shfl_xor(ss, off);
  __shared__ float wsum[4];
  __shared__ float srstd;
  int wid = threadIdx.x >> 6;
  if ((threadIdx.x & 63) == 0) wsum[wid] = ss;
  __syncthreads();
  if (threadIdx.x == 0) {
    float tot = wsum[0] + wsum[1] + wsum[2] + wsum[3];
    srstd = rsqrtf(tot * (1.f / H_) + EPS_);
  }
  __syncthreads();
  float r = srstd;
  float* orow = out + (size_t)t * H_;
  for (int c = threadIdx.x; c < H_; c += 256) orow[c] = xr[c] * r * w[c];
}

// ---------------- generic fp32 GEMM  C[M,N] = A[M,K] @ B[K,N] ----------------
__global__ __launch_bounds__(256) void gemm_nn(const float* __restrict__ A,
                                               const float* __restrict__ B,
                                               float* __restrict__ C,
                                               int M, int K, int N) {
  __shared__ float As[64][17];
  __shared__ float Bs[16][65];
  int m0 = blockIdx.y * 64, n0 = blockIdx.x * 64;
  int tid = threadIdx.x;
  int tx = tid & 15, ty = tid >> 4;
  float acc[4][4] = {};
  for (int k0 = 0; k0 < K; k0 += 16) {
    for (int e = tid; e < 1024; e += 256) {
      int row = e >> 4, kk = e & 15;
      float va = 0.f;
      if (m0 + row < M) va = A[(size_t)(m0 + row) * K + k0 + kk];
      As[row][kk] = va;
      int kb = e >> 6, col = e & 63;
      float vb = 0.f;
      if (n0 + col < N) vb = B[(size_t)(k0 + kb) * N + n0 + col];
      Bs[kb][col] = vb;
    }
    __syncthreads();
#pragma unroll
    for (int kk = 0; kk < 16; ++kk) {
      float a[4], b[4];
#pragma unroll
      for (int ii = 0; ii < 4; ++ii) a[ii] = As[ty * 4 + ii][kk];
#pragma unroll
      for (int jj = 0; jj < 4; ++jj) b[jj] = Bs[kk][tx * 4 + jj];
#pragma unroll
      for (int ii = 0; ii < 4; ++ii)
#pragma unroll
        for (int jj = 0; jj < 4; ++jj) acc[ii][jj] += a[ii] * b[jj];
    }
    __syncthreads();
  }
  for (int ii = 0; ii < 4; ++ii) {
    int r = m0 + ty * 4 + ii;
    if (r < M)
      for (int jj = 0; jj < 4; ++jj) {
        int c = n0 + tx * 4 + jj;
        if (c < N) C[(size_t)r * N + c] = acc[ii][jj];
      }
  }
}

// ------- routed GEMM-BT: C[r][n] = dot(A[gather[r]], B_e[n][:K]), r in expert segment -------
__global__ __launch_bounds__(256) void gemm_bt_routed(const float* __restrict__ A, int lda,
                                                      const float* __restrict__ B,
                                                      float* __restrict__ C, int ldc,
                                                      const int* __restrict__ gather,
                                                      const int* __restrict__ offsets,
                                                      int N, int K) {
  int e = blockIdx.z;
  int rs = offsets[e], re = offsets[e + 1];
  int r0 = rs + blockIdx.y * 64;
  if (r0 >= re) return;
  int n0 = blockIdx.x * 64;
  const float* Be = B + (size_t)e * N * K;
  __shared__ float As[64][17];
  __shared__ float Bs[64][17];
  int tid = threadIdx.x;
  int tx = tid & 15, ty = tid >> 4;
  float acc[4][4] = {};
  for (int k0 = 0; k0 < K; k0 += 16) {
    for (int ee = tid; ee < 1024; ee += 256) {
      int row = ee >> 4, kk = ee & 15;
      int r = r0 + row;
      float va = 0.f;
      if (r < re) {
        int src = gather ? gather[r] : r;
        va = A[(size_t)src * lda + k0 + kk];
      }
      As[row][kk] = va;
      Bs[row][kk] = Be[(size_t)(n0 + row) * K + k0 + kk];
    }
    __syncthreads();
#pragma unroll
    for (int kk = 0; kk < 16; ++kk) {
      float a[4], b[4];
#pragma unroll
      for (int ii = 0; ii < 4; ++ii) a[ii] = As[ty * 4 + ii][kk];
#pragma unroll
      for (int jj = 0; jj < 4; ++jj) b[jj] = Bs[tx * 4 + jj][kk];
#pragma unroll
      for (int ii = 0; ii < 4; ++ii)
#pragma unroll
        for (int jj = 0; jj < 4; ++jj) acc[ii][jj] += a[ii] * b[jj];
    }
    __syncthreads();
  }
  for (int ii = 0; ii < 4; ++ii) {
    int r = r0 + ty * 4 + ii;
    if (r < re)
      for (int jj = 0; jj < 4; ++jj)
        C[(size_t)r * ldc + n0 + tx * 4 + jj] = acc[ii][jj];
  }
}

// ---------------- RoPE (NeoX) in-place on q and k inside qkv ----------------
__global__ __launch_bounds__(256) void rope_k(float* __restrict__ qkv) {
  int idx = blockIdx.x * 256 + threadIdx.x;
  const int total = T_ * (NH_ + NKV_) * 64;
  if (idx >= total) return;
  int i = idx & 63;
  int head = (idx >> 6) % (NH_ + NKV_);
  int t = idx / (64 * (NH_ + NKV_));
  float* base = qkv + (size_t)t * QKVN + (head < NH_ ? head * HD_ : NH_ * HD_ + (head - NH_) * HD_);
  float inv = powf(10000.f, -(float)i * (1.f / 64.f));
  float ang = (float)t * inv;
  float c = cosf(ang), s = sinf(ang);
  float x1 = base[i], x2 = base[i + 64];
  base[i]      = x1 * c - x2 * s;
  base[i + 64] = x2 * c + x1 * s;
}

// ---------------- flash attention, 16x16 tiles, fp32 ----------------
__global__ __launch_bounds__(256) void flash_attn_k(const float* __restrict__ qkv,
                                                    float* __restrict__ out) {
  const int h = blockIdx.x;        // 0..15
  const int qt = blockIdx.y;       // 0..127
  const int kvh = h >> 2;
  const int tid = threadIdx.x;
  const int i = tid >> 4, j = tid & 15;
  __shared__ float sQ[16][129], sK[16][129], sV[16][129], sO[16][129];
  __shared__ float sP[16][16];
  __shared__ float sm[16], sl[16];
  const float scale = 0.08838834764831845f;  // 1/sqrt(128)
  for (int e = tid; e < 16 * 128; e += 256) {
    int r = e >> 7, d = e & 127;
    sQ[r][d] = qkv[(size_t)(qt * 16 + r) * QKVN + h * HD_ + d];
    sO[r][d] = 0.f;
  }
  if (tid < 16) { sm[tid] = -INFINITY; sl[tid] = 0.f; }
  __syncthreads();
  for (int kt = 0; kt <= qt; ++kt) {
    int s0 = kt * 16;
    for (int e = tid; e < 16 * 128; e += 256) {
      int r = e >> 7, d = e & 127;
      sK[r][d] = qkv[(size_t)(s0 + r) * QKVN + NH_ * HD_ + kvh * HD_ + d];
      sV[r][d] = qkv[(size_t)(s0 + r) * QKVN + NH_ * HD_ + NKV_ * HD_ + kvh * HD_ + d];
    }
    __syncthreads();
    float s = 0.f;
    for (int d = 0; d < 128; ++d) s += sQ[i][d] * sK[j][d];
    s *= scale;
    int qi = qt * 16 + i, kj = s0 + j;
    bool masked = kj > qi;
    if (masked) s = -INFINITY;
    float rowmax = s;
#pragma unroll
    for (int off = 8; off > 0; off >>= 1) rowmax = fmaxf(rowmax, __shfl_xor(rowmax, off));
    float m_old = sm[i];
    float m_new = fmaxf(m_old, rowmax);
    float p = masked ? 0.f : expf(s - m_new);
    float rowsum = p;
#pragma unroll
    for (int off = 8; off > 0; off >>= 1) rowsum += __shfl_xor(rowsum, off);
    float alpha = expf(m_old - m_new);
    __syncthreads();
    if (j == 0) { sm[i] = m_new; sl[i] = sl[i] * alpha + rowsum; }
    sP[i][j] = p;
    __syncthreads();
    for (int dd = 0; dd < 8; ++dd) {
      int d = j * 8 + dd;
      float o = sO[i][d] * alpha;
#pragma unroll
      for (int jj = 0; jj < 16; ++jj) o += sP[i][jj] * sV[jj][d];
      sO[i][d] = o;
    }
    __syncthreads();
  }
  float linv = 1.f / sl[i];
  for (int dd = 0; dd < 8; ++dd) {
    int d = j * 8 + dd;
    out[(size_t)(qt * 16 + i) * (NH_ * HD_) + h * HD_ + d] = sO[i][d] * linv;
  }
}

// ---------------- elementwise helpers ----------------
__global__ __launch_bounds__(256) void add_k(const float* __restrict__ a, float* __restrict__ b, int n) {
  int idx = blockIdx.x * 256 + threadIdx.x;
  if (idx < n) b[idx] = a[idx] + b[idx];   // b += a (in place)
}

__global__ __launch_bounds__(256) void silu_mul_k(const float* __restrict__ in, float* __restrict__ out,
                                                  int rows, int n) {
  int idx = blockIdx.x * 256 + threadIdx.x;
  if (idx >= rows * n) return;
  int r = idx / n, c = idx - r * n;
  float g = in[(size_t)r * 2 * n + c];
  float u = in[(size_t)r * 2 * n + n + c];
  out[(size_t)r * n + c] = (g / (1.f + expf(-g))) * u;
}

// ---------------- gating: softmax + top2 + counts ----------------
__global__ __launch_bounds__(256) void gate_topk_k(const float* __restrict__ logits,
                                                   int* __restrict__ counts,
                                                   int* __restrict__ topi,
                                                   float* __restrict__ topw) {
  int t = blockIdx.x * 256 + threadIdx.x;
  if (t >= T_) return;
  float l[E_];
  float mx = -INFINITY;
  for (int e = 0; e < E_; ++e) { l[e] = logits[t * E_ + e]; mx = fmaxf(mx, l[e]); }
  for (int e = 0; e < E_; ++e) l[e] = expf(l[e] - mx);
  int i0 = 0;
  for (int e = 1; e < E_; ++e) if (l[e] > l[i0]) i0 = e;
  int i1 = (i0 == 0) ? 1 : 0;
  for (int e = 0; e < E_; ++e) if (e != i0 && l[e] > l[i1]) i1 = e;
  float p0 = l[i0], p1 = l[i1];
  float inv = 1.f / (p0 + p1);
  topi[t * 2] = i0; topi[t * 2 + 1] = i1;
  topw[t * 2] = p0 * inv; topw[t * 2 + 1] = p1 * inv;
  atomicAdd(&counts[i0], 1);
  atomicAdd(&counts[i1], 1);
}

__global__ void make_offsets_k(const int* __restrict__ counts, int* __restrict__ offsets,
                               int* __restrict__ fill) {
  if (threadIdx.x == 0 && blockIdx.x == 0) {
    int acc = 0;
    for (int e = 0; e < E_; ++e) { offsets[e] = acc; fill[e] = acc; acc += counts[e]; }
    offsets[E_] = acc;
  }
}

__global__ __launch_bounds__(256) void scatter_k(const int* __restrict__ topi,
                                                 int* __restrict__ fill,
                                                 int* __restrict__ routed_token,
                                                 int* __restrict__ token_rows) {
  int t = blockIdx.x * 256 + threadIdx.x;
  if (t >= T_) return;
  for (int k = 0; k < 2; ++k) {
    int e = topi[t * 2 + k];
    int row = atomicAdd(&fill[e], 1);
    routed_token[row] = t;
    token_rows[t * 2 + k] = row;
  }
}

// ---------------- final combine ----------------
__global__ __launch_bounds__(256) void final_k(const float* __restrict__ resid_attn,
                                               const float* __restrict__ res_mlp,
                                               const float* __restrict__ moe_rows,
                                               const int* __restrict__ token_rows,
                                               const float* __restrict__ topw,
                                               float* __restrict__ out) {
  int idx = blockIdx.x * 256 + threadIdx.x;
  if (idx >= T_ * H_) return;
  int t = idx >> 11, c = idx & (H_ - 1);
  int r0 = token_rows[t * 2], r1 = token_rows[t * 2 + 1];
  float w0 = topw[t * 2], w1 = topw[t * 2 + 1];
  out[idx] = resid_attn[idx] + res_mlp[idx]
           + w0 * moe_rows[(size_t)r0 * H_ + c]
           + w1 * moe_rows[(size_t)r1 * H_ + c];
}

extern "C" void kernel_launch(void* const* d_in, const int* in_sizes, int n_in,
                              void* d_out, int out_size, void* d_ws, size_t ws_size,
                              hipStream_t stream) {
  const float* hidden  = (const float*)d_in[0];
  const float* ln_in_w = (const float*)d_in[1];
  const float* ln_post_w = (const float*)d_in[2];
  const float* ln_res_w  = (const float*)d_in[3];
  const float* wqkv    = (const float*)d_in[4];
  const float* wo      = (const float*)d_in[5];
  const float* res_w13 = (const float*)d_in[6];
  const float* res_w2  = (const float*)d_in[7];
  const float* gate_w  = (const float*)d_in[8];
  const float* ws_moe  = (const float*)d_in[9];
  const float* w2s     = (const float*)d_in[10];
  float* out = (float*)d_out;

  const size_t TH = (size_t)T_ * H_;
  char* p = (char*)d_ws;
  auto falloc = [&](size_t elems) { float* q = (float*)p; p += elems * sizeof(float); return q; };
  float* x_ln_in   = falloc(TH);
  float* x_ln_post = falloc(TH);
  float* qkv       = falloc((size_t)T_ * QKVN);
  float* attn_out  = falloc(TH);           // later reused as x_ln_res
  float* attn_proj = falloc(TH);           // becomes resid_attn in place
  float* gu        = falloc((size_t)T_ * 4096); // reused as moe_gu (4096x2048)
  float* hmid      = falloc(TH);           // reused as moe_hmid (4096x1024)
  float* res_mlp   = falloc(TH);
  float* moe_rows  = falloc(2 * TH);       // 4096 x 2048
  float* logits    = falloc((size_t)T_ * E_);
  float* topw      = falloc((size_t)T_ * 2);
  auto ialloc = [&](size_t elems) { int* q = (int*)p; p += elems * sizeof(int); return q; };
  int* counts       = ialloc(16);
  int* offsets      = ialloc(24);
  int* fill         = ialloc(16);
  int* topi         = ialloc((size_t)T_ * 2);
  int* token_rows   = ialloc((size_t)T_ * 2);
  int* routed_token = ialloc((size_t)T_ * 2);

  float* x_ln_res  = attn_out;  // buffer reuse after wo GEMM
  float* resid_attn = attn_proj;
  float* moe_gu   = gu;
  float* moe_hmid = hmid;

  // 1-2: RMSNorms of hidden
  rmsnorm_k<<<T_, 256, 0, stream>>>(hidden, ln_in_w, x_ln_in);
  rmsnorm_k<<<T_, 256, 0, stream>>>(hidden, ln_post_w, x_ln_post);
  // 3: qkv = x_ln_in @ wqkv
  gemm_nn<<<dim3(QKVN / 64, T_ / 64), 256, 0, stream>>>(x_ln_in, wqkv, qkv, T_, H_, QKVN);
  // 4: rope
  rope_k<<<(T_ * (NH_ + NKV_) * 64 + 255) / 256, 256, 0, stream>>>(qkv);
  // 5: attention
  flash_attn_k<<<dim3(NH_, T_ / 16), 256, 0, stream>>>(qkv, attn_out);
  // 6: attn_proj = attn_out @ wo
  gemm_nn<<<dim3(H_ / 64, T_ / 64), 256, 0, stream>>>(attn_out, wo, attn_proj, T_, H_, H_);
  // 7: resid_attn = hidden + attn_proj (in place into attn_proj)
  add_k<<<(int)(TH / 256), 256, 0, stream>>>(hidden, attn_proj, (int)TH);
  // 8: x_ln_res = rmsnorm(resid_attn, ln_res_w)
  rmsnorm_k<<<T_, 256, 0, stream>>>(resid_attn, ln_res_w, x_ln_res);
  // 9: gu = x_ln_res @ res_w13
  gemm_nn<<<dim3(4096 / 64, T_ / 64), 256, 0, stream>>>(x_ln_res, res_w13, gu, T_, H_, 4096);
  // 10: hmid = silu_and_mul(gu)
  silu_mul_k<<<(int)(TH / 256), 256, 0, stream>>>(gu, hmid, T_, H_);
  // 11: res_mlp = hmid @ res_w2
  gemm_nn<<<dim3(H_ / 64, T_ / 64), 256, 0, stream>>>(hmid, res_w2, res_mlp, T_, H_, H_);
  // 12: logits = x_ln_post @ gate_w
  gemm_nn<<<dim3(1, T_ / 64), 256, 0, stream>>>(x_ln_post, gate_w, logits, T_, H_, E_);
  // 13: gate top2
  hipMemsetAsync(counts, 0, 16 * sizeof(int), stream);
  gate_topk_k<<<T_ / 256, 256, 0, stream>>>(logits, counts, topi, topw);
  // 14-15: offsets + scatter
  make_offsets_k<<<1, 64, 0, stream>>>(counts, offsets, fill);
  scatter_k<<<T_ / 256, 256, 0, stream>>>(topi, fill, routed_token, token_rows);
  // 16: moe_gu[r] = x_ln_post[token[r]] @ ws[e].T
  gemm_bt_routed<<<dim3(2 * I_ / 64, T_ / 64, E_), 256, 0, stream>>>(
      x_ln_post, H_, ws_moe, moe_gu, 2 * I_, routed_token, offsets, 2 * I_, H_);
  // 17: moe_hmid = silu_and_mul(moe_gu)  (4096 rows x 1024)
  silu_mul_k<<<(int)(TH / 256), 256, 0, stream>>>(moe_gu, moe_hmid, 2 * T_, I_);
  // 18: moe_rows[r] = moe_hmid[r] @ w2s[e].T
  gemm_bt_routed<<<dim3(H_ / 64, T_ / 64, E_), 256, 0, stream>>>(
      moe_hmid, I_, w2s, moe_rows, H_, nullptr, offsets, H_, I_);
  // 19: final out
  final_k<<<(int)(TH / 256), 256, 0, stream>>>(resid_attn, res_mlp, moe_rows, token_rows, topw, out);
}

// Round 3
// 2014.949 us; speedup vs baseline: 3.3330x; 3.3330x over previous
//
#include <hip/hip_runtime.h>
#include <math.h>

#define T_    2048
#define H_    2048
#define NH_   16
#define NKV_  4
#define HD_   128
#define I_    1024
#define E_    16
#define QKVN  3072
#define EPS_  1e-5f

typedef __attribute__((ext_vector_type(8))) __bf16 bf16x8;
typedef __attribute__((ext_vector_type(4))) float f32x4;

__device__ __forceinline__ unsigned short f2bf(float f) {
  union { float f; unsigned u; } v; v.f = f;
  return (unsigned short)((v.u + 0x7fffu + ((v.u >> 16) & 1u)) >> 16);
}
__device__ __forceinline__ float bf2f(unsigned short h) {
  union { unsigned u; float f; } v; v.u = ((unsigned)h) << 16;
  return v.f;
}
__device__ __forceinline__ void ldsdma16(const void* g, void* l) {
  __builtin_amdgcn_global_load_lds((const __attribute__((address_space(1))) void*)g,
                                   (__attribute__((address_space(3))) void*)l, 16, 0, 0);
}

// ---------------- RMSNorm -> bf16 ----------------
__global__ __launch_bounds__(256) void rmsnorm_bf_k(const float* __restrict__ x,
                                                    const float* __restrict__ w,
                                                    unsigned short* __restrict__ out) {
  int t = blockIdx.x;
  const float* xr = x + (size_t)t * H_;
  float ss = 0.f;
  for (int c = threadIdx.x; c < H_; c += 256) { float v = xr[c]; ss += v * v; }
#pragma unroll
  for (int off = 32; off > 0; off >>= 1) ss += __shfl_xor(ss, off);
  __shared__ float wsum[4];
  __shared__ float srstd;
  int wid = threadIdx.x >> 6;
  if ((threadIdx.x & 63) == 0) wsum[wid] = ss;
  __syncthreads();
  if (threadIdx.x == 0) {
    float tot = wsum[0] + wsum[1] + wsum[2] + wsum[3];
    srstd = rsqrtf(tot * (1.f / H_) + EPS_);
  }
  __syncthreads();
  float r = srstd;
  unsigned short* orow = out + (size_t)t * H_;
  for (int c = threadIdx.x; c < H_; c += 256) orow[c] = f2bf(xr[c] * r * w[c]);
}

// ---------------- transpose + fp32->bf16:  in[K][N] -> out[N][K] ----------------
__global__ __launch_bounds__(256) void transp_bf_k(const float* __restrict__ in,
                                                   unsigned short* __restrict__ out,
                                                   int K, int N) {
  __shared__ float tile[32][33];
  int k0 = blockIdx.y * 32, n0 = blockIdx.x * 32;
  int c = threadIdx.x & 31, r = threadIdx.x >> 5;  // r: 0..7
  for (int rr = r; rr < 32; rr += 8)
    tile[rr][c] = in[(size_t)(k0 + rr) * N + n0 + c];
  __syncthreads();
  for (int rr = r; rr < 32; rr += 8)
    out[(size_t)(n0 + rr) * K + k0 + c] = f2bf(tile[c][rr]);
}

// ---------------- MFMA GEMM: C[M,N] = A[M,K](bf16) @ Bt[N,K](bf16)^T ----------------
#define BM 128
#define BN 128
#define BK 32
__global__ __launch_bounds__(256) void gemm_mfma_tn(const unsigned short* __restrict__ A,
                                                    const unsigned short* __restrict__ Bt,
                                                    float* __restrict__ C,
                                                    int M, int N, int K) {
  __shared__ unsigned short sA[BM * BK];
  __shared__ unsigned short sB[BN * BK];
  const int tid = threadIdx.x;
  const int wave = tid >> 6;
  const int lane = tid & 63;
  const int m0 = blockIdx.y * BM;
  const int n0 = blockIdx.x * BN;
  const int wm = (wave & 1) * 64;
  const int wn = (wave >> 1) * 64;
  const int srow = wave * 32 + (lane >> 2);
  const int sch  = (lane & 3) * 8;
  const unsigned short* ga0 = A  + (size_t)(m0 + srow) * K + sch;
  const unsigned short* ga1 = A  + (size_t)(m0 + srow + 16) * K + sch;
  const unsigned short* gb0 = Bt + (size_t)(n0 + srow) * K + sch;
  const unsigned short* gb1 = Bt + (size_t)(n0 + srow + 16) * K + sch;
  unsigned short* la0 = &sA[(wave * 32) * BK];
  unsigned short* la1 = &sA[(wave * 32 + 16) * BK];
  unsigned short* lb0 = &sB[(wave * 32) * BK];
  unsigned short* lb1 = &sB[(wave * 32 + 16) * BK];
  const int frm = lane & 15;
  const int quad = lane >> 4;
  f32x4 acc[4][4] = {};
  for (int k0 = 0; k0 < K; k0 += BK) {
    ldsdma16(ga0, la0);
    ldsdma16(ga1, la1);
    ldsdma16(gb0, lb0);
    ldsdma16(gb1, lb1);
    ga0 += BK; ga1 += BK; gb0 += BK; gb1 += BK;
    __syncthreads();
    bf16x8 af[4], bf[4];
#pragma unroll
    for (int i = 0; i < 4; ++i) {
      af[i] = *(const bf16x8*)&sA[(wm + i * 16 + frm) * BK + quad * 8];
      bf[i] = *(const bf16x8*)&sB[(wn + i * 16 + frm) * BK + quad * 8];
    }
#pragma unroll
    for (int i = 0; i < 4; ++i)
#pragma unroll
      for (int j = 0; j < 4; ++j)
        acc[i][j] = __builtin_amdgcn_mfma_f32_16x16x32_bf16(af[i], bf[j], acc[i][j], 0, 0, 0);
    __syncthreads();
  }
#pragma unroll
  for (int i = 0; i < 4; ++i) {
    int rbase = m0 + wm + i * 16 + quad * 4;
#pragma unroll
    for (int j = 0; j < 4; ++j) {
      int c = n0 + wn + j * 16 + frm;
      float* cp = C + (size_t)rbase * N + c;
#pragma unroll
      for (int r = 0; r < 4; ++r) cp[(size_t)r * N] = acc[i][j][r];
    }
  }
}

// ------- routed MFMA GEMM: C[r][n] = A[gather[r]] . B_e[n][:K]; B fp32 staged->bf16 -------
__global__ __launch_bounds__(256) void gemm_mfma_routed(const unsigned short* __restrict__ A, int lda,
                                                        const float* __restrict__ B,
                                                        float* __restrict__ C, int ldc,
                                                        const int* __restrict__ gather,
                                                        const int* __restrict__ offsets,
                                                        int N, int K) {
  const int e = blockIdx.z;
  const int rs = offsets[e], re = offsets[e + 1];
  const int r0 = rs + blockIdx.y * BM;
  if (r0 >= re) return;
  const int n0 = blockIdx.x * BN;
  const float* Be = B + (size_t)e * N * K;
  __shared__ unsigned short sA[BM * BK];
  __shared__ unsigned short sB[BN * BK];
  const int tid = threadIdx.x;
  const int wave = tid >> 6;
  const int lane = tid & 63;
  const int wm = (wave & 1) * 64;
  const int wn = (wave >> 1) * 64;
  int ra0 = r0 + wave * 32 + (lane >> 2);
  int ra1 = ra0 + 16;
  int c0 = ra0 < re ? ra0 : re - 1;
  int c1 = ra1 < re ? ra1 : re - 1;
  int src0 = gather ? gather[c0] : c0;
  int src1 = gather ? gather[c1] : c1;
  const int sch = (lane & 3) * 8;
  const unsigned short* ga0 = A + (size_t)src0 * lda + sch;
  const unsigned short* ga1 = A + (size_t)src1 * lda + sch;
  unsigned short* la0 = &sA[(wave * 32) * BK];
  unsigned short* la1 = &sA[(wave * 32 + 16) * BK];
  const int brow = tid >> 1;
  const int bk = (tid & 1) * 16;
  const float* bp0 = Be + (size_t)(n0 + brow) * K + bk;
  unsigned short* bdst = &sB[brow * BK + bk];
  const int frm = lane & 15;
  const int quad = lane >> 4;
  f32x4 acc[4][4] = {};
  for (int k0 = 0; k0 < K; k0 += BK) {
    ldsdma16(ga0, la0);
    ldsdma16(ga1, la1);
    ga0 += BK; ga1 += BK;
    const float* bp = bp0 + k0;
#pragma unroll
    for (int q = 0; q < 4; ++q) {
      float4 v = *(const float4*)(bp + q * 4);
      bdst[q * 4 + 0] = f2bf(v.x);
      bdst[q * 4 + 1] = f2bf(v.y);
      bdst[q * 4 + 2] = f2bf(v.z);
      bdst[q * 4 + 3] = f2bf(v.w);
    }
    __syncthreads();
    bf16x8 af[4], bfr[4];
#pragma unroll
    for (int i = 0; i < 4; ++i) {
      af[i]  = *(const bf16x8*)&sA[(wm + i * 16 + frm) * BK + quad * 8];
      bfr[i] = *(const bf16x8*)&sB[(wn + i * 16 + frm) * BK + quad * 8];
    }
#pragma unroll
    for (int i = 0; i < 4; ++i)
#pragma unroll
      for (int j = 0; j < 4; ++j)
        acc[i][j] = __builtin_amdgcn_mfma_f32_16x16x32_bf16(af[i], bfr[j], acc[i][j], 0, 0, 0);
    __syncthreads();
  }
#pragma unroll
  for (int i = 0; i < 4; ++i) {
    int rbase = r0 + wm + i * 16 + quad * 4;
#pragma unroll
    for (int j = 0; j < 4; ++j) {
      int c = n0 + wn + j * 16 + frm;
#pragma unroll
      for (int r = 0; r < 4; ++r) {
        int rr = rbase + r;
        if (rr < re) C[(size_t)rr * ldc + c] = acc[i][j][r];
      }
    }
  }
}

// ---------------- RoPE (NeoX) in-place on q and k inside qkv ----------------
__global__ __launch_bounds__(256) void rope_k(float* __restrict__ qkv) {
  int idx = blockIdx.x * 256 + threadIdx.x;
  const int total = T_ * (NH_ + NKV_) * 64;
  if (idx >= total) return;
  int i = idx & 63;
  int head = (idx >> 6) % (NH_ + NKV_);
  int t = idx / (64 * (NH_ + NKV_));
  float* base = qkv + (size_t)t * QKVN + (head < NH_ ? head * HD_ : NH_ * HD_ + (head - NH_) * HD_);
  float inv = powf(10000.f, -(float)i * (1.f / 64.f));
  float ang = (float)t * inv;
  float c = cosf(ang), s = sinf(ang);
  float x1 = base[i], x2 = base[i + 64];
  base[i]      = x1 * c - x2 * s;
  base[i + 64] = x2 * c + x1 * s;
}

// ---------------- flash attention, 16x16 tiles, fp32, bf16 out ----------------
__global__ __launch_bounds__(256) void flash_attn_k(const float* __restrict__ qkv,
                                                    unsigned short* __restrict__ out) {
  const int h = blockIdx.x;
  const int qt = blockIdx.y;
  const int kvh = h >> 2;
  const int tid = threadIdx.x;
  const int i = tid >> 4, j = tid & 15;
  __shared__ float sQ[16][132], sK[16][132], sV[16][132], sO[16][132];
  __shared__ float sP[16][16];
  __shared__ float sm[16], sl[16];
  const float scale = 0.08838834764831845f;  // 1/sqrt(128)
  for (int e = tid; e < 16 * 128; e += 256) {
    int r = e >> 7, d = e & 127;
    sQ[r][d] = qkv[(size_t)(qt * 16 + r) * QKVN + h * HD_ + d];
    sO[r][d] = 0.f;
  }
  if (tid < 16) { sm[tid] = -INFINITY; sl[tid] = 0.f; }
  __syncthreads();
  for (int kt = 0; kt <= qt; ++kt) {
    int s0 = kt * 16;
    for (int e = tid; e < 16 * 128; e += 256) {
      int r = e >> 7, d = e & 127;
      sK[r][d] = qkv[(size_t)(s0 + r) * QKVN + NH_ * HD_ + kvh * HD_ + d];
      sV[r][d] = qkv[(size_t)(s0 + r) * QKVN + NH_ * HD_ + NKV_ * HD_ + kvh * HD_ + d];
    }
    __syncthreads();
    float s = 0.f;
    const float4* q4 = (const float4*)&sQ[i][0];
    const float4* k4 = (const float4*)&sK[j][0];
    for (int d4 = 0; d4 < 32; ++d4) {
      float4 a = q4[d4], b = k4[d4];
      s += a.x * b.x + a.y * b.y + a.z * b.z + a.w * b.w;
    }
    s *= scale;
    int qi = qt * 16 + i, kj = s0 + j;
    bool masked = kj > qi;
    if (masked) s = -INFINITY;
    float rowmax = s;
#pragma unroll
    for (int off = 8; off > 0; off >>= 1) rowmax = fmaxf(rowmax, __shfl_xor(rowmax, off));
    float m_old = sm[i];
    float m_new = fmaxf(m_old, rowmax);
    float p = masked ? 0.f : expf(s - m_new);
    float rowsum = p;
#pragma unroll
    for (int off = 8; off > 0; off >>= 1) rowsum += __shfl_xor(rowsum, off);
    float alpha = expf(m_old - m_new);
    __syncthreads();
    if (j == 0) { sm[i] = m_new; sl[i] = sl[i] * alpha + rowsum; }
    sP[i][j] = p;
    __syncthreads();
    for (int dd = 0; dd < 8; ++dd) {
      int d = dd * 16 + j;
      float o = sO[i][d] * alpha;
#pragma unroll
      for (int jj = 0; jj < 16; ++jj) o += sP[i][jj] * sV[jj][d];
      sO[i][d] = o;
    }
    __syncthreads();
  }
  float linv = 1.f / sl[i];
  for (int dd = 0; dd < 8; ++dd) {
    int d = dd * 16 + j;
    out[(size_t)(qt * 16 + i) * (NH_ * HD_) + h * HD_ + d] = f2bf(sO[i][d] * linv);
  }
}

// ---------------- elementwise ----------------
__global__ __launch_bounds__(256) void add_k(const float* __restrict__ a, float* __restrict__ b, int n) {
  int idx = blockIdx.x * 256 + threadIdx.x;
  if (idx < n) b[idx] = a[idx] + b[idx];
}

__global__ __launch_bounds__(256) void silu_mul_bf_k(const float* __restrict__ in,
                                                     unsigned short* __restrict__ out,
                                                     int rows, int n) {
  int idx = blockIdx.x * 256 + threadIdx.x;
  if (idx >= rows * n) return;
  int r = idx / n, c = idx - r * n;
  float g = in[(size_t)r * 2 * n + c];
  float u = in[(size_t)r * 2 * n + n + c];
  out[(size_t)r * n + c] = f2bf((g / (1.f + expf(-g))) * u);
}

// ---------- gate logits, full fp32 path: inline rmsnorm(hidden, ln_post_w) . gate_w ----------
// Routing is discontinuous (top-2 argmax) — must NOT see bf16-rounded inputs.
__global__ __launch_bounds__(256) void gate_fp32_k(const float* __restrict__ hidden,
                                                   const float* __restrict__ lnw,
                                                   const float* __restrict__ gw,
                                                   float* __restrict__ logits) {
  int t = blockIdx.x;
  const float* xr = hidden + (size_t)t * H_;
  float ss = 0.f;
  for (int c = threadIdx.x; c < H_; c += 256) { float v = xr[c]; ss += v * v; }
#pragma unroll
  for (int off = 32; off > 0; off >>= 1) ss += __shfl_xor(ss, off);
  __shared__ float wsum[4];
  __shared__ float srstd;
  int wid = threadIdx.x >> 6;
  if ((threadIdx.x & 63) == 0) wsum[wid] = ss;
  __syncthreads();
  if (threadIdx.x == 0) {
    float tot = wsum[0] + wsum[1] + wsum[2] + wsum[3];
    srstd = rsqrtf(tot * (1.f / H_) + EPS_);
  }
  __syncthreads();
  float r = srstd;
  int e = threadIdx.x & 15;
  int chunk = threadIdx.x >> 4;
  float s = 0.f;
  for (int c = chunk * 128; c < chunk * 128 + 128; ++c)
    s += xr[c] * r * lnw[c] * gw[c * E_ + e];
  __shared__ float red[16][16];
  red[chunk][e] = s;
  __syncthreads();
  if (threadIdx.x < 16) {
    float tot = 0.f;
    for (int c2 = 0; c2 < 16; ++c2) tot += red[c2][threadIdx.x];
    logits[(size_t)t * E_ + threadIdx.x] = tot;
  }
}

// ---------------- gating: softmax + top2 + counts ----------------
__global__ __launch_bounds__(256) void gate_topk_k(const float* __restrict__ logits,
                                                   int* __restrict__ counts,
                                                   int* __restrict__ topi,
                                                   float* __restrict__ topw) {
  int t = blockIdx.x * 256 + threadIdx.x;
  if (t >= T_) return;
  float l[E_];
  float mx = -INFINITY;
  for (int e = 0; e < E_; ++e) { l[e] = logits[t * E_ + e]; mx = fmaxf(mx, l[e]); }
  for (int e = 0; e < E_; ++e) l[e] = expf(l[e] - mx);
  int i0 = 0;
  for (int e = 1; e < E_; ++e) if (l[e] > l[i0]) i0 = e;
  int i1 = (i0 == 0) ? 1 : 0;
  for (int e = 0; e < E_; ++e) if (e != i0 && l[e] > l[i1]) i1 = e;
  float p0 = l[i0], p1 = l[i1];
  float inv = 1.f / (p0 + p1);
  topi[t * 2] = i0; topi[t * 2 + 1] = i1;
  topw[t * 2] = p0 * inv; topw[t * 2 + 1] = p1 * inv;
  atomicAdd(&counts[i0], 1);
  atomicAdd(&counts[i1], 1);
}

__global__ void make_offsets_k(const int* __restrict__ counts, int* __restrict__ offsets,
                               int* __restrict__ fill) {
  if (threadIdx.x == 0 && blockIdx.x == 0) {
    int acc = 0;
    for (int e = 0; e < E_; ++e) { offsets[e] = acc; fill[e] = acc; acc += counts[e]; }
    offsets[E_] = acc;
  }
}

__global__ __launch_bounds__(256) void scatter_k(const int* __restrict__ topi,
                                                 int* __restrict__ fill,
                                                 int* __restrict__ routed_token,
                                                 int* __restrict__ token_rows) {
  int t = blockIdx.x * 256 + threadIdx.x;
  if (t >= T_) return;
  for (int k = 0; k < 2; ++k) {
    int e = topi[t * 2 + k];
    int row = atomicAdd(&fill[e], 1);
    routed_token[row] = t;
    token_rows[t * 2 + k] = row;
  }
}

// ---------------- final combine ----------------
__global__ __launch_bounds__(256) void final_k(const float* __restrict__ resid_attn,
                                               const float* __restrict__ res_mlp,
                                               const float* __restrict__ moe_rows,
                                               const int* __restrict__ token_rows,
                                               const float* __restrict__ topw,
                                               float* __restrict__ out) {
  int idx = blockIdx.x * 256 + threadIdx.x;
  if (idx >= T_ * H_) return;
  int t = idx >> 11, c = idx & (H_ - 1);
  int r0 = token_rows[t * 2], r1 = token_rows[t * 2 + 1];
  float w0 = topw[t * 2], w1 = topw[t * 2 + 1];
  out[idx] = resid_attn[idx] + res_mlp[idx]
           + w0 * moe_rows[(size_t)r0 * H_ + c]
           + w1 * moe_rows[(size_t)r1 * H_ + c];
}

extern "C" void kernel_launch(void* const* d_in, const int* in_sizes, int n_in,
                              void* d_out, int out_size, void* d_ws, size_t ws_size,
                              hipStream_t stream) {
  const float* hidden    = (const float*)d_in[0];
  const float* ln_in_w   = (const float*)d_in[1];
  const float* ln_post_w = (const float*)d_in[2];
  const float* ln_res_w  = (const float*)d_in[3];
  const float* wqkv      = (const float*)d_in[4];
  const float* wo        = (const float*)d_in[5];
  const float* res_w13   = (const float*)d_in[6];
  const float* res_w2    = (const float*)d_in[7];
  const float* gate_w    = (const float*)d_in[8];
  const float* ws_moe    = (const float*)d_in[9];
  const float* w2s       = (const float*)d_in[10];
  float* out = (float*)d_out;

  const size_t TH = (size_t)T_ * H_;
  char* p = (char*)d_ws;
  auto alloc = [&](size_t bytes) { char* q = p; p += (bytes + 255) & ~(size_t)255; return q; };
  unsigned short* wqkv_t = (unsigned short*)alloc((size_t)QKVN * H_ * 2);
  unsigned short* wo_t   = (unsigned short*)alloc((size_t)H_ * H_ * 2);
  unsigned short* w13_t  = (unsigned short*)alloc((size_t)4096 * H_ * 2);
  unsigned short* w2_t   = (unsigned short*)alloc((size_t)H_ * H_ * 2);
  float* qkv      = (float*)alloc((size_t)T_ * QKVN * 4);   // reused as res_mlp
  float* gu       = (float*)alloc((size_t)T_ * 4096 * 4);   // reused as moe_gu
  float* moe_rows = (float*)alloc((size_t)4096 * H_ * 4);
  float* resid    = (float*)alloc(TH * 4);
  unsigned short* bfA          = (unsigned short*)alloc(TH * 2); // x_ln_in -> hmid -> moe_hmid
  unsigned short* x_ln_post_bf = (unsigned short*)alloc(TH * 2);
  unsigned short* attn_bf      = (unsigned short*)alloc(TH * 2); // attn_out -> x_ln_res
  float* logits = (float*)alloc((size_t)T_ * E_ * 4);
  float* topw   = (float*)alloc((size_t)T_ * 2 * 4);
  int* counts       = (int*)alloc(16 * 4);
  int* offsets      = (int*)alloc(24 * 4);
  int* fill         = (int*)alloc(16 * 4);
  int* topi         = (int*)alloc((size_t)T_ * 2 * 4);
  int* token_rows   = (int*)alloc((size_t)T_ * 2 * 4);
  int* routed_token = (int*)alloc((size_t)T_ * 2 * 4);
  float* res_mlp = qkv;
  float* moe_gu  = gu;

  // weight transposes (fp32 [K][N] -> bf16 [N][K])
  transp_bf_k<<<dim3(QKVN / 32, H_ / 32), 256, 0, stream>>>(wqkv, wqkv_t, H_, QKVN);
  transp_bf_k<<<dim3(H_ / 32, H_ / 32), 256, 0, stream>>>(wo, wo_t, H_, H_);
  transp_bf_k<<<dim3(4096 / 32, H_ / 32), 256, 0, stream>>>(res_w13, w13_t, H_, 4096);
  transp_bf_k<<<dim3(H_ / 32, H_ / 32), 256, 0, stream>>>(res_w2, w2_t, H_, H_);
  // rmsnorms
  rmsnorm_bf_k<<<T_, 256, 0, stream>>>(hidden, ln_in_w, bfA);
  rmsnorm_bf_k<<<T_, 256, 0, stream>>>(hidden, ln_post_w, x_ln_post_bf);
  // qkv = x_ln_in @ wqkv
  gemm_mfma_tn<<<dim3(QKVN / BN, T_ / BM), 256, 0, stream>>>(bfA, wqkv_t, qkv, T_, QKVN, H_);
  // rope + attention
  rope_k<<<(T_ * (NH_ + NKV_) * 64 + 255) / 256, 256, 0, stream>>>(qkv);
  flash_attn_k<<<dim3(NH_, T_ / 16), 256, 0, stream>>>(qkv, attn_bf);
  // attn proj -> resid; add residual
  gemm_mfma_tn<<<dim3(H_ / BN, T_ / BM), 256, 0, stream>>>(attn_bf, wo_t, resid, T_, H_, H_);
  add_k<<<(int)(TH / 256), 256, 0, stream>>>(hidden, resid, (int)TH);
  // residual MLP
  rmsnorm_bf_k<<<T_, 256, 0, stream>>>(resid, ln_res_w, attn_bf);   // x_ln_res
  gemm_mfma_tn<<<dim3(4096 / BN, T_ / BM), 256, 0, stream>>>(attn_bf, w13_t, gu, T_, 4096, H_);
  silu_mul_bf_k<<<(int)(TH / 256), 256, 0, stream>>>(gu, bfA, T_, H_);  // hmid
  gemm_mfma_tn<<<dim3(H_ / BN, T_ / BM), 256, 0, stream>>>(bfA, w2_t, res_mlp, T_, H_, H_);
  // gate + routing (fp32 logits from hidden — routing must not see bf16 rounding)
  gate_fp32_k<<<T_, 256, 0, stream>>>(hidden, ln_post_w, gate_w, logits);
  hipMemsetAsync(counts, 0, 16 * sizeof(int), stream);
  gate_topk_k<<<T_ / 256, 256, 0, stream>>>(logits, counts, topi, topw);
  make_offsets_k<<<1, 64, 0, stream>>>(counts, offsets, fill);
  scatter_k<<<T_ / 256, 256, 0, stream>>>(topi, fill, routed_token, token_rows);
  // MoE expert GEMMs (B fp32 staged -> bf16 in kernel)
  gemm_mfma_routed<<<dim3(2 * I_ / BN, 4096 / BM, E_), 256, 0, stream>>>(
      x_ln_post_bf, H_, ws_moe, moe_gu, 2 * I_, routed_token, offsets, 2 * I_, H_);
  silu_mul_bf_k<<<(int)(TH / 256), 256, 0, stream>>>(moe_gu, bfA, 2 * T_, I_);  // moe_hmid
  gemm_mfma_routed<<<dim3(H_ / BN, 4096 / BM, E_), 256, 0, stream>>>(
      bfA, I_, w2s, moe_rows, H_, nullptr, offsets, H_, I_);
  // final combine
  final_k<<<(int)(TH / 256), 256, 0, stream>>>(resid, res_mlp, moe_rows, token_rows, topw, out);
}